// Round 8
// baseline (280.466 us; speedup 1.0000x reference)
//
#include <hip/hip_runtime.h>
#include <hip/hip_bf16.h>
#include <hip/hip_fp16.h>
#include <math.h>

#define BN 4096
#define LH 200
#define LFB 100
#define ED 64
#define PD 32
#define HD 32
#define NP 3168    // P + PNET = 32 + 3136
#define IV 100000

typedef unsigned int uint32;
typedef __attribute__((ext_vector_type(8))) short short8;
typedef __attribute__((ext_vector_type(8))) _Float16 half8;
typedef __attribute__((ext_vector_type(4))) float f32x4;
union BF8 { uint32 u[4]; short8 v; };
union HF8 { uint32 u[4]; half8 v; };

__device__ __forceinline__ uint32 f2bf_pack(float x, float y) {
    uint32 ux = __float_as_uint(x);
    uint32 uy = __float_as_uint(y);
    uint32 bx = (ux + 0x7fffu + ((ux >> 16) & 1u)) >> 16;
    uint32 by = (uy + 0x7fffu + ((uy >> 16) & 1u)) >> 16;
    return (by << 16) | (bx & 0xffffu);
}

__device__ __forceinline__ uint32 f2h_pack(float x, float y) {
    __half2 h = __floats2half2_rn(x, y);
    return *(reinterpret_cast<uint32*>(&h));
}

// ---------------------------------------------------------------------------
// Kernel 0: item_emb fp32 -> bf16 packed words (IEB, 32 words/row)
// ---------------------------------------------------------------------------
__global__ __launch_bounds__(256) void k0_cvt(
    const float* __restrict__ src, uint32* __restrict__ dst)
{
    const int i = blockIdx.x * 256 + threadIdx.x;   // < IV*32 = 3.2M exact
    const float2 v = ((const float2*)src)[i];
    dst[i] = f2bf_pack(v.x, v.y);
}

// ---------------------------------------------------------------------------
// Kernel 0b: Wp (64 x NP fp32) -> WpB bf16 packed, layout [n][kw] kw=k-pair
// ---------------------------------------------------------------------------
__global__ __launch_bounds__(256) void k0b_cvt_wp(
    const float* __restrict__ Wp, uint32* __restrict__ WpB)
{
    const int n = blockIdx.x * 256 + threadIdx.x;
    const int kw = blockIdx.y;
    if (n < NP) {
        const float a = Wp[(size_t)(2*kw)*NP + n];
        const float b = Wp[(size_t)(2*kw+1)*NP + n];
        WpB[(size_t)n*32 + kw] = f2bf_pack(a, b);
    }
}

// ---------------------------------------------------------------------------
// Kernel 0c: Wf1/Wf2/Wf3 fp32 -> fp16 packed B-fragment layouts w/ K-padding.
// ---------------------------------------------------------------------------
__global__ __launch_bounds__(256) void k0c_cvt_wf(
    const float* __restrict__ Wf1, const float* __restrict__ Wf2,
    const float* __restrict__ Wf3, uint32* __restrict__ W1B,
    uint32* __restrict__ W2B, uint32* __restrict__ W3B)
{
    const int i = blockIdx.x * 256 + threadIdx.x;
    if (i < 13312) {
        const int n = i >> 6, kw = i & 63;
        W1B[i] = (n < 200) ? f2h_pack(Wf1[(size_t)(2*kw)*200 + n],
                                      Wf1[(size_t)(2*kw+1)*200 + n]) : 0u;
    } else if (i < 22272) {
        const int j = i - 13312, n = j / 112, kw = j % 112;
        W2B[j] = (kw < 100) ? f2h_pack(Wf2[(size_t)(2*kw)*80 + n],
                                       Wf2[(size_t)(2*kw+1)*80 + n]) : 0u;
    } else if (i < 25344) {
        const int j = i - 22272, n = j / 48, kw = j % 48;
        W3B[j] = (kw < 40) ? f2h_pack(Wf3[(size_t)(2*kw)*64 + n],
                                      Wf3[(size_t)(2*kw+1)*64 + n]) : 0u;
    }
}

// ---------------------------------------------------------------------------
// Kernel 1: gathers + attention + pooling.  grid=B, block=256.
// No LDS staging: rows gathered directly for scores AND pooling (2x line
// touches but ~6 KB LDS -> 8 blocks/CU of latency hiding).
// ---------------------------------------------------------------------------
__global__ __launch_bounds__(256, 8) void k1_gather_attn(
    const uint32* __restrict__ IEB,
    const float* __restrict__ item_emb, const float* __restrict__ user_emb,
    const float* __restrict__ W_if, const float* __restrict__ b_if,
    const float* __restrict__ W_uf, const float* __restrict__ b_uf,
    const float* __restrict__ item_features, const float* __restrict__ user_features,
    const int* __restrict__ user_id, const int* __restrict__ target_item_id,
    const int* __restrict__ hist_id, const int* __restrict__ hist_len,
    const int* __restrict__ pos_fb, const int* __restrict__ pos_mask,
    float* __restrict__ FUE, float* __restrict__ FIE, uint32* __restrict__ PINB)
{
    const int b = blockIdx.x;
    const int t = threadIdx.x;
    const int w = t >> 6;
    const int lane = t & 63;

    __shared__ __align__(16) float tgt[64];
    __shared__ float feats[256];
    __shared__ float ufe[64];
    __shared__ float scoreS[256];
    __shared__ float wred[8];
    __shared__ float part[256];
    __shared__ float part2[256];
    __shared__ int   hids[200];
    __shared__ int   cpi[104];
    __shared__ int   ptot[2];

    const int hl = hist_len[b];
    if (t < 200) hids[t] = hist_id[(size_t)b*LH + t];
    feats[t] = (t < 128) ? item_features[(size_t)b*128 + t]
                         : user_features[(size_t)b*128 + (t-128)];
    if (t < 64) tgt[t] = item_emb[(size_t)target_item_id[b]*64 + t];

    bool myAct = false; int myPid = 0;
    if (t < LFB) {
        myAct = pos_mask[(size_t)b*LFB + t] != 0;
        myPid = pos_fb[(size_t)b*LFB + t];
    }
    __syncthreads();   // sync0: tgt/hids/feats

    // ---- scores: direct gather of own row (8 independent uint4 loads) ----
    float sc = -1e9f;
    if (t < hl) {
        const uint4* rp = (const uint4*)(IEB + (size_t)hids[t]*32);
        float acc = 0.f;
        #pragma unroll
        for (int c4 = 0; c4 < 8; c4++) {
            const uint4 u = rp[c4];
            const uint32 ws[4] = {u.x, u.y, u.z, u.w};
            #pragma unroll
            for (int j = 0; j < 4; j++) {
                const float2 tf = ((const float2*)tgt)[c4*4 + j];
                acc = fmaf(__uint_as_float(ws[j] << 16),         tf.x, acc);
                acc = fmaf(__uint_as_float(ws[j] & 0xffff0000u), tf.y, acc);
            }
        }
        sc = acc * 0.125f;
    }

    // ---- pos-feedback compaction ballot (waves 0,1) ----
    int pre = 0;
    if (w < 2) {
        const unsigned long long bal = __ballot(myAct);
        pre = __popcll(bal & ((1ull << lane) - 1ull));
        if (lane == 0) ptot[w] = __popcll(bal);
    }

    float m = sc;
    #pragma unroll
    for (int off = 32; off >= 1; off >>= 1) m = fmaxf(m, __shfl_xor(m, off, 64));
    if (lane == 0) wred[w] = m;
    __syncthreads();   // sync1: wred(max), ptot

    const int nP = ptot[0] + ptot[1];
    if (w < 2 && myAct) cpi[((w == 1) ? ptot[0] : 0) + pre] = myPid;

    const float mx = fmaxf(fmaxf(wred[0], wred[1]), fmaxf(wred[2], wred[3]));
    const float ev = __expf(sc - mx);
    float s = ev;
    #pragma unroll
    for (int off = 32; off >= 1; off >>= 1) s += __shfl_xor(s, off, 64);
    if (lane == 0) wred[4 + w] = s;

    // ---- feature embeddings (wave 0: item, wave 1: user) ----
    if (w == 0) {
        float acc = b_if[lane];
        #pragma unroll 4
        for (int k = 0; k < 128; k++) acc = fmaf(feats[k], W_if[k*64 + lane], acc);
        FIE[(size_t)b*64 + lane] = tgt[lane] + 1.f / (1.f + __expf(-acc));
    } else if (w == 1) {
        float acc = b_uf[lane];
        #pragma unroll 4
        for (int k = 0; k < 128; k++) acc = fmaf(feats[128 + k], W_uf[k*64 + lane], acc);
        ufe[lane] = 1.f / (1.f + __expf(-acc));
    }
    __syncthreads();   // sync2: wred sums, cpi visible

    const float S = wred[4] + wred[5] + wred[6] + wred[7];
    if (t < 200) scoreS[t] = ev / S;

    // ---- pos-mean gather over compacted list ----
    const int wk = lane >> 1;
    const int comp = lane & 1;
    {
        float pacc = 0.f;
        for (int i = w; i < nP; i += 4) {
            const uint32 wd = IEB[(size_t)cpi[i]*32 + wk];
            pacc += __uint_as_float(comp ? (wd & 0xffff0000u) : (wd << 16));
        }
        part2[w*64 + lane] = pacc;
    }
    __syncthreads();   // sync3: scoreS visible

    // ---- pooled: direct re-gather of valid rows (interleaved) ----
    {
        float acc = 0.f;
        for (int l = w; l < hl; l += 4) {
            const uint32 word = IEB[(size_t)hids[l]*32 + wk];
            const float hv = __uint_as_float(comp ? (word & 0xffff0000u) : (word << 16));
            acc = fmaf(scoreS[l], hv, acc);
        }
        part[w*64 + lane] = acc;
    }
    __syncthreads();   // sync4

    if (t < 64) {
        const float pooled = part[t] + part[64+t] + part[128+t] + part[192+t];
        const float pinv = (part2[t] + part2[64+t] + part2[128+t] + part2[192+t]) / (float)nP;
        FUE[(size_t)b*64 + t] = user_emb[(size_t)user_id[b]*64 + t] + ufe[t] + pooled;
        const float po = __shfl_xor(pinv, 1, 64);
        if ((t & 1) == 0) PINB[(size_t)b*32 + (t >> 1)] = f2bf_pack(pinv, po);
    }
}

// ---------------------------------------------------------------------------
// Kernel 2: total_prompt = relu(PIN @ Wp + bp) via MFMA bf16.
// ---------------------------------------------------------------------------
__global__ __launch_bounds__(256) void k2_prompt_gemm(
    const uint32* __restrict__ PINB, const uint32* __restrict__ WpB,
    const float* __restrict__ bp, float* __restrict__ TP32,
    uint32* __restrict__ TPN)
{
    __shared__ uint32 As[64*36];
    __shared__ uint32 Bs[128*36];
    __shared__ float bps[128];
    const int t = threadIdx.x;
    const int m0 = blockIdx.y * 64;
    const int n0 = blockIdx.x * 128;

    {
        const int m = t >> 2, kw0 = (t & 3) * 8;
        const uint4 u0 = *(const uint4*)&PINB[(size_t)(m0+m)*32 + kw0];
        const uint4 u1 = *(const uint4*)&PINB[(size_t)(m0+m)*32 + kw0 + 4];
        *(uint4*)&As[m*36 + kw0]     = u0;
        *(uint4*)&As[m*36 + kw0 + 4] = u1;
    }
    {
        const int n = t >> 1, kw0 = (t & 1) * 16;
        const int gn = n0 + n;
        if (gn < NP) {
            #pragma unroll
            for (int j = 0; j < 4; j++) {
                const uint4 u = *(const uint4*)&WpB[(size_t)gn*32 + kw0 + 4*j];
                *(uint4*)&Bs[n*36 + kw0 + 4*j] = u;
            }
        } else {
            #pragma unroll
            for (int j = 0; j < 16; j++) Bs[n*36 + kw0 + j] = 0u;
        }
    }
    if (t < 128) bps[t] = (n0 + t < NP) ? bp[n0 + t] : 0.f;
    __syncthreads();

    const int w = t >> 6, lane = t & 63, ml = lane & 15, q = lane >> 4;

    BF8 a0, a1;
    { uint4 u = *(const uint4*)&As[(w*16+ml)*36 + q*4];      a0.u[0]=u.x; a0.u[1]=u.y; a0.u[2]=u.z; a0.u[3]=u.w; }
    { uint4 u = *(const uint4*)&As[(w*16+ml)*36 + 16 + q*4]; a1.u[0]=u.x; a1.u[1]=u.y; a1.u[2]=u.z; a1.u[3]=u.w; }

    f32x4 c[8];
    #pragma unroll
    for (int nb = 0; nb < 8; nb++) {
        BF8 b0, b1;
        { uint4 u = *(const uint4*)&Bs[(nb*16+ml)*36 + q*4];      b0.u[0]=u.x; b0.u[1]=u.y; b0.u[2]=u.z; b0.u[3]=u.w; }
        { uint4 u = *(const uint4*)&Bs[(nb*16+ml)*36 + 16 + q*4]; b1.u[0]=u.x; b1.u[1]=u.y; b1.u[2]=u.z; b1.u[3]=u.w; }
        f32x4 cc = {0.f, 0.f, 0.f, 0.f};
        cc = __builtin_amdgcn_mfma_f32_16x16x32_bf16(a0.v, b0.v, cc, 0, 0, 0);
        cc = __builtin_amdgcn_mfma_f32_16x16x32_bf16(a1.v, b1.v, cc, 0, 0, 0);
        c[nb] = cc;
    }

    #pragma unroll
    for (int nb = 0; nb < 8; nb++) {
        const int n = n0 + nb*16 + ml;
        const float bv = bps[nb*16 + ml];
        #pragma unroll
        for (int r = 0; r < 4; r++) {
            const int m = m0 + w*16 + q*4 + r;
            const float v = fmaxf(c[nb][r] + bv, 0.f);
            const float vp = __shfl_xor(v, 1, 64);
            if (n < 32) {
                TP32[(size_t)m*32 + n] = v;
            } else if (n < NP && (ml & 1) == 0) {
                TPN[(size_t)m*1568 + ((n - 32) >> 1)] = f2bf_pack(v, vp);
            }
        }
    }
}

// ---------------------------------------------------------------------------
// Kernel 3: prompt hypernetwork via MFMA 16x16x32 bf16.  grid=B, block=256.
// ---------------------------------------------------------------------------
__global__ __launch_bounds__(256) void k3_prompt_mlp(
    const uint32* __restrict__ IEB,
    const int* __restrict__ pos_fb, const int* __restrict__ pos_mask,
    const int* __restrict__ neg_fb, const int* __restrict__ neg_mask,
    const uint32* __restrict__ TPN,
    float* __restrict__ POS_PE, float* __restrict__ out)
{
    const int b = blockIdx.x, t = threadIdx.x;
    const int w = t >> 6, lane = t & 63;
    const int ml = lane & 15, q = lane >> 4;

    __shared__ uint32 w1b[32*36];
    __shared__ uint32 w2b[32*20];
    __shared__ float b1s[32], b2s[32];
    __shared__ float mPs[208], mNs[208];
    __shared__ int cids[208];
    __shared__ int tot[4];
    __shared__ float Hs[4][16*36];
    __shared__ float wps[4][4][16];

    bool act = false; int id = 0;
    if (t < LFB) {
        act = pos_mask[(size_t)b*LFB + t] != 0;
        id  = pos_fb[(size_t)b*LFB + t];
    } else if (t >= 128 && t < 128 + LFB) {
        act = neg_mask[(size_t)b*LFB + (t-128)] != 0;
        id  = neg_fb[(size_t)b*LFB + (t-128)];
    }
    const unsigned long long bal = __ballot(act);
    const int pre = __popcll(bal & ((1ull << lane) - 1ull));
    if (lane == 0) tot[w] = __popcll(bal);
    if (t < 208) cids[t] = 0;

    const uint32* pnw = TPN + (size_t)b*1568;
    #pragma unroll
    for (int it = 0; it < 4; it++) {
        const int i = t + 256*it;
        const int n = i >> 5, kw = i & 31;
        const uint32 wa = pnw[kw*32 + (n >> 1)];
        const uint32 wb = pnw[kw*32 + 16 + (n >> 1)];
        const uint32 h0 = (n & 1) ? (wa >> 16) : (wa & 0xffffu);
        const uint32 h1 = (n & 1) ? (wb >> 16) : (wb & 0xffffu);
        w1b[n*36 + kw] = h0 | (h1 << 16);
    }
    #pragma unroll
    for (int it = 0; it < 2; it++) {
        const int i = t + 256*it;
        const int n = i >> 4, kw = i & 15;
        const uint32 wa = pnw[1040 + kw*32 + (n >> 1)];
        const uint32 wb = pnw[1040 + kw*32 + 16 + (n >> 1)];
        const uint32 h0 = (n & 1) ? (wa >> 16) : (wa & 0xffffu);
        const uint32 h1 = (n & 1) ? (wb >> 16) : (wb & 0xffffu);
        w2b[n*20 + kw] = h0 | (h1 << 16);
    }
    if (t < 16) {
        const uint32 wa = pnw[1024 + t];
        b1s[2*t]   = __uint_as_float(wa << 16);
        b1s[2*t+1] = __uint_as_float(wa & 0xffff0000u);
        const uint32 wb = pnw[1552 + t];
        b2s[2*t]   = __uint_as_float(wb << 16);
        b2s[2*t+1] = __uint_as_float(wb & 0xffff0000u);
    }
    __syncthreads();   // sync1

    const int nP = tot[0] + tot[1];
    const int nN = tot[2] + tot[3];
    const int R  = nP + nN;
    const int T  = (R + 15) >> 4;
    {
        int base = 0;
        if (w == 1) base = tot[0];
        else if (w == 2) base = nP;
        else if (w == 3) base = nP + tot[2];
        if (act) cids[base + pre] = id;
    }
    if (t < 208) {
        mPs[t] = (t < nP) ? 1.f : 0.f;
        mNs[t] = (t >= nP && t < R) ? 1.f : 0.f;
    }

    BF8 bf100, bf110, bf101, bf111, bf20, bf21;
    {
        uint4 u;
        u = *(const uint4*)&w1b[ml*36 + q*4];            bf100.u[0]=u.x; bf100.u[1]=u.y; bf100.u[2]=u.z; bf100.u[3]=u.w;
        u = *(const uint4*)&w1b[ml*36 + 16 + q*4];       bf110.u[0]=u.x; bf110.u[1]=u.y; bf110.u[2]=u.z; bf110.u[3]=u.w;
        u = *(const uint4*)&w1b[(16+ml)*36 + q*4];       bf101.u[0]=u.x; bf101.u[1]=u.y; bf101.u[2]=u.z; bf101.u[3]=u.w;
        u = *(const uint4*)&w1b[(16+ml)*36 + 16 + q*4];  bf111.u[0]=u.x; bf111.u[1]=u.y; bf111.u[2]=u.z; bf111.u[3]=u.w;
        u = *(const uint4*)&w2b[ml*20 + q*4];            bf20.u[0]=u.x;  bf20.u[1]=u.y;  bf20.u[2]=u.z;  bf20.u[3]=u.w;
        u = *(const uint4*)&w2b[(16+ml)*20 + q*4];       bf21.u[0]=u.x;  bf21.u[1]=u.y;  bf21.u[2]=u.z;  bf21.u[3]=u.w;
    }
    __syncthreads();   // sync2

    float accP0=0.f, accP1=0.f, accN0=0.f, accN1=0.f;
    float* hsw = Hs[w];

    for (int tile = w; tile < T; tile += 4) {
        const int g = tile*16 + ml;
        const uint32* rowp = IEB + (size_t)cids[g]*32;
        BF8 a0, a1;
        { uint4 u = *(const uint4*)(rowp + q*4);      a0.u[0]=u.x; a0.u[1]=u.y; a0.u[2]=u.z; a0.u[3]=u.w; }
        { uint4 u = *(const uint4*)(rowp + 16 + q*4); a1.u[0]=u.x; a1.u[1]=u.y; a1.u[2]=u.z; a1.u[3]=u.w; }

        f32x4 c0 = {0.f,0.f,0.f,0.f}, c1 = {0.f,0.f,0.f,0.f};
        c0 = __builtin_amdgcn_mfma_f32_16x16x32_bf16(a0.v, bf100.v, c0, 0, 0, 0);
        c0 = __builtin_amdgcn_mfma_f32_16x16x32_bf16(a1.v, bf110.v, c0, 0, 0, 0);
        c1 = __builtin_amdgcn_mfma_f32_16x16x32_bf16(a0.v, bf101.v, c1, 0, 0, 0);
        c1 = __builtin_amdgcn_mfma_f32_16x16x32_bf16(a1.v, bf111.v, c1, 0, 0, 0);

        #pragma unroll
        for (int r = 0; r < 4; r++) {
            const int row = q*4 + r;
            hsw[row*36 + ml]      = fmaxf(c0[r] + b1s[ml],      0.f);
            hsw[row*36 + 16 + ml] = fmaxf(c1[r] + b1s[16 + ml], 0.f);
        }
        asm volatile("s_waitcnt lgkmcnt(0)" ::: "memory");

        const float4 h0 = *(const float4*)&hsw[ml*36 + q*8];
        const float4 h1 = *(const float4*)&hsw[ml*36 + q*8 + 4];
        BF8 a2;
        a2.u[0] = f2bf_pack(h0.x, h0.y);
        a2.u[1] = f2bf_pack(h0.z, h0.w);
        a2.u[2] = f2bf_pack(h1.x, h1.y);
        a2.u[3] = f2bf_pack(h1.z, h1.w);

        f32x4 d0 = {0.f,0.f,0.f,0.f}, d1 = {0.f,0.f,0.f,0.f};
        d0 = __builtin_amdgcn_mfma_f32_16x16x32_bf16(a2.v, bf20.v, d0, 0, 0, 0);
        d1 = __builtin_amdgcn_mfma_f32_16x16x32_bf16(a2.v, bf21.v, d1, 0, 0, 0);

        #pragma unroll
        for (int r = 0; r < 4; r++) {
            const int g2 = tile*16 + q*4 + r;
            const float o0 = d0[r] + b2s[ml];
            const float o1 = d1[r] + b2s[16 + ml];
            accP0 = fmaf(mPs[g2], o0, accP0);
            accP1 = fmaf(mPs[g2], o1, accP1);
            accN0 = fmaf(mNs[g2], o0, accN0);
            accN1 = fmaf(mNs[g2], o1, accN1);
        }
    }

    accP0 += __shfl_xor(accP0, 16, 64); accP0 += __shfl_xor(accP0, 32, 64);
    accP1 += __shfl_xor(accP1, 16, 64); accP1 += __shfl_xor(accP1, 32, 64);
    accN0 += __shfl_xor(accN0, 16, 64); accN0 += __shfl_xor(accN0, 32, 64);
    accN1 += __shfl_xor(accN1, 16, 64); accN1 += __shfl_xor(accN1, 32, 64);
    if (lane < 16) {
        wps[w][0][lane] = accP0;
        wps[w][1][lane] = accP1;
        wps[w][2][lane] = accN0;
        wps[w][3][lane] = accN1;
    }
    __syncthreads();

    if (t < 32) {
        const int nt = t >> 4, p = t & 15;
        const float pp = wps[0][nt][p] + wps[1][nt][p] + wps[2][nt][p] + wps[3][nt][p];
        const float nn = wps[0][2+nt][p] + wps[1][2+nt][p] + wps[2][2+nt][p] + wps[3][2+nt][p];
        POS_PE[(size_t)b*32 + t] = pp;
        const float x = nn - pp;
        out[BN + (size_t)b*32 + t] = fmaxf(x, 0.f) + log1pf(__expf(-fabsf(x)));
    }
}

// ---------------------------------------------------------------------------
// Kernel 4: fused 3-layer fusion MLP + final dot via MFMA fp16.
// ---------------------------------------------------------------------------
__global__ __launch_bounds__(256) void k4_fusion(
    const float* __restrict__ FUE, const float* __restrict__ FIE,
    const float* __restrict__ POS_PE, const float* __restrict__ TP32,
    const uint32* __restrict__ W1B, const uint32* __restrict__ W2B,
    const uint32* __restrict__ W3B,
    const float* __restrict__ bf1, const float* __restrict__ bf2,
    float* __restrict__ out)
{
    const int b0 = blockIdx.x * 16;
    const int t = threadIdx.x;
    const int w = t >> 6, lane = t & 63, ml = lane & 15, q = lane >> 4;

    __shared__ uint32 w1s[208*68];
    __shared__ uint32 w2s[80*116];
    __shared__ uint32 w3s[64*52];
    __shared__ uint32 fin[16*68];
    __shared__ uint32 h1w[16*116];
    __shared__ uint32 h2w[16*52];
    __shared__ float fuels[16*68];
    __shared__ float b1s[208], b2s[80];
    __shared__ float part4[4][16];

    for (int i = t; i < 13312; i += 256) w1s[(i >> 6)*68 + (i & 63)] = W1B[i];
    for (int i = t; i < 8960; i += 256)  w2s[(i / 112)*116 + (i % 112)] = W2B[i];
    for (int i = t; i < 3072; i += 256)  w3s[(i / 48)*52 + (i % 48)] = W3B[i];

    #pragma unroll
    for (int it = 0; it < 4; it++) {
        const int i = t + 256*it;
        const int m2 = i >> 6, kw = i & 63;
        const int row = b0 + m2;
        float a, c;
        if (kw < 32)      { const float2 v = *(const float2*)&FIE[(size_t)row*64 + 2*kw];          a = v.x; c = v.y; }
        else if (kw < 48) { const float2 v = *(const float2*)&POS_PE[(size_t)row*32 + 2*kw - 64];  a = v.x; c = v.y; }
        else              { const float2 v = *(const float2*)&TP32[(size_t)row*32 + 2*kw - 96];    a = v.x; c = v.y; }
        fin[m2*68 + kw] = f2h_pack(a, c);
        fuels[m2*68 + kw] = FUE[(size_t)row*64 + kw];
    }
    if (t < 208) b1s[t] = (t < 200) ? bf1[t] : 0.f;
    if (t < 80)  b2s[t] = bf2[t];
    if (t < 128) {
        h1w[(t >> 3)*116 + 104 + (t & 7)] = 0u;
        h2w[(t >> 3)*52 + 40 + (t & 7)] = 0u;
    }
    __syncthreads();

    HF8 a1f[4];
    #pragma unroll
    for (int s = 0; s < 4; s++) {
        const uint4 u = *(const uint4*)&fin[ml*68 + s*16 + q*4];
        a1f[s].u[0] = u.x; a1f[s].u[1] = u.y; a1f[s].u[2] = u.z; a1f[s].u[3] = u.w;
    }
    for (int nt = w; nt < 13; nt += 4) {
        const uint32* wrow = &w1s[(16*nt + ml)*68];
        f32x4 c = {0.f, 0.f, 0.f, 0.f};
        #pragma unroll
        for (int s = 0; s < 4; s++) {
            HF8 bfm;
            const uint4 u = *(const uint4*)&wrow[s*16 + q*4];
            bfm.u[0] = u.x; bfm.u[1] = u.y; bfm.u[2] = u.z; bfm.u[3] = u.w;
            c = __builtin_amdgcn_mfma_f32_16x16x32_f16(a1f[s].v, bfm.v, c, 0, 0, 0);
        }
        const float bv = b1s[16*nt + ml];
        #pragma unroll
        for (int r = 0; r < 4; r++) {
            const float v = fmaxf(c[r] + bv, 0.f);
            const float vp = __shfl_xor(v, 1, 64);
            if ((ml & 1) == 0)
                h1w[(q*4 + r)*116 + 8*nt + (ml >> 1)] = f2h_pack(v, vp);
        }
    }
    __syncthreads();

    HF8 a2f[7];
    #pragma unroll
    for (int s = 0; s < 7; s++) {
        const uint4 u = *(const uint4*)&h1w[ml*116 + s*16 + q*4];
        a2f[s].u[0] = u.x; a2f[s].u[1] = u.y; a2f[s].u[2] = u.z; a2f[s].u[3] = u.w;
    }
    for (int nt = w; nt < 5; nt += 4) {
        const uint32* wrow = &w2s[(16*nt + ml)*116];
        f32x4 c = {0.f, 0.f, 0.f, 0.f};
        #pragma unroll
        for (int s = 0; s < 7; s++) {
            HF8 bfm;
            const uint4 u = *(const uint4*)&wrow[s*16 + q*4];
            bfm.u[0] = u.x; bfm.u[1] = u.y; bfm.u[2] = u.z; bfm.u[3] = u.w;
            c = __builtin_amdgcn_mfma_f32_16x16x32_f16(a2f[s].v, bfm.v, c, 0, 0, 0);
        }
        const float bv = b2s[16*nt + ml];
        #pragma unroll
        for (int r = 0; r < 4; r++) {
            const float v = fmaxf(c[r] + bv, 0.f);
            const float vp = __shfl_xor(v, 1, 64);
            if ((ml & 1) == 0)
                h2w[(q*4 + r)*52 + 8*nt + (ml >> 1)] = f2h_pack(v, vp);
        }
    }
    __syncthreads();

    {
        const int nt = w;
        const uint32* wrow = &w3s[(16*nt + ml)*52];
        f32x4 c = {0.f, 0.f, 0.f, 0.f};
        #pragma unroll
        for (int s = 0; s < 3; s++) {
            HF8 afm, bfm;
            const uint4 ua = *(const uint4*)&h2w[ml*52 + s*16 + q*4];
            afm.u[0] = ua.x; afm.u[1] = ua.y; afm.u[2] = ua.z; afm.u[3] = ua.w;
            const uint4 ub = *(const uint4*)&wrow[s*16 + q*4];
            bfm.u[0] = ub.x; bfm.u[1] = ub.y; bfm.u[2] = ub.z; bfm.u[3] = ub.w;
            c = __builtin_amdgcn_mfma_f32_16x16x32_f16(afm.v, bfm.v, c, 0, 0, 0);
        }
        #pragma unroll
        for (int r = 0; r < 4; r++) {
            float p = c[r] * fuels[(q*4 + r)*68 + 16*nt + ml];
            p += __shfl_xor(p, 1, 64);
            p += __shfl_xor(p, 2, 64);
            p += __shfl_xor(p, 4, 64);
            p += __shfl_xor(p, 8, 64);
            if (ml == 0) part4[w][q*4 + r] = p;
        }
    }
    __syncthreads();

    if (t < 16) out[b0 + t] = part4[0][t] + part4[1][t] + part4[2][t] + part4[3][t];
}

// ---------------------------------------------------------------------------
extern "C" void kernel_launch(void* const* d_in, const int* in_sizes, int n_in,
                              void* d_out, int out_size, void* d_ws, size_t ws_size,
                              hipStream_t stream)
{
    const float* item_emb       = (const float*)d_in[0];
    const float* user_emb       = (const float*)d_in[1];
    const float* W_if           = (const float*)d_in[2];
    const float* b_if           = (const float*)d_in[3];
    const float* W_uf           = (const float*)d_in[4];
    const float* b_uf           = (const float*)d_in[5];
    const float* Wp             = (const float*)d_in[6];
    const float* bp             = (const float*)d_in[7];
    const float* Wf1            = (const float*)d_in[8];
    const float* bf1            = (const float*)d_in[9];
    const float* Wf2            = (const float*)d_in[10];
    const float* bf2            = (const float*)d_in[11];
    const float* Wf3            = (const float*)d_in[12];
    const float* item_features  = (const float*)d_in[13];
    const float* user_features  = (const float*)d_in[14];
    const int*   user_id        = (const int*)d_in[15];
    const int*   target_item_id = (const int*)d_in[16];
    const int*   history_item_id= (const int*)d_in[17];
    const int*   history_len    = (const int*)d_in[18];
    const int*   pos_fb         = (const int*)d_in[19];
    const int*   pos_mask       = (const int*)d_in[20];
    const int*   neg_fb         = (const int*)d_in[21];
    const int*   neg_mask       = (const int*)d_in[22];

    float* out = (float*)d_out;
    float* ws  = (float*)d_ws;

    uint32* IEB  = (uint32*)ws;                       // IV*32
    uint32* WpB  = IEB + (size_t)IV*32;               // NP*32
    uint32* W1B  = WpB + (size_t)NP*32;               // 13312
    uint32* W2B  = W1B + 13312;                       // 8960
    uint32* W3B  = W2B + 8960;                        // 3072
    uint32* PINB = W3B + 3072;                        // BN*32
    float*  FUE  = (float*)(PINB + (size_t)BN*32);
    float*  FIE  = FUE + (size_t)BN*64;
    float*  TP32 = FIE + (size_t)BN*64;               // BN*32
    uint32* TPN  = (uint32*)(TP32 + (size_t)BN*32);   // BN*1568
    float*  PPE  = (float*)(TPN + (size_t)BN*1568);

    k0_cvt<<<dim3(IV*32/256), dim3(256), 0, stream>>>(item_emb, IEB);
    k0b_cvt_wp<<<dim3(13, 32), dim3(256), 0, stream>>>(Wp, WpB);
    k0c_cvt_wf<<<dim3(99), dim3(256), 0, stream>>>(Wf1, Wf2, Wf3, W1B, W2B, W3B);

    k1_gather_attn<<<dim3(BN), dim3(256), 0, stream>>>(
        IEB, item_emb, user_emb, W_if, b_if, W_uf, b_uf,
        item_features, user_features, user_id, target_item_id,
        history_item_id, history_len, pos_fb, pos_mask,
        FUE, FIE, PINB);

    k2_prompt_gemm<<<dim3(25, 64), dim3(256), 0, stream>>>(PINB, WpB, bp, TP32, TPN);

    k3_prompt_mlp<<<dim3(BN), dim3(256), 0, stream>>>(
        IEB, pos_fb, pos_mask, neg_fb, neg_mask, TPN, PPE, out);

    k4_fusion<<<dim3(BN/16), dim3(256), 0, stream>>>(
        FUE, FIE, PPE, TP32, W1B, W2B, W3B, bf1, bf2, out);
}

// Round 9
// 237.947 us; speedup vs baseline: 1.1787x; 1.1787x over previous
//
#include <hip/hip_runtime.h>
#include <hip/hip_bf16.h>
#include <hip/hip_fp16.h>
#include <math.h>

#define BN 4096
#define LH 200
#define LFB 100
#define ED 64
#define PD 32
#define HD 32
#define NP 3168    // P + PNET = 32 + 3136
#define IV 100000

typedef unsigned int uint32;
typedef __attribute__((ext_vector_type(8))) short short8;
typedef __attribute__((ext_vector_type(8))) _Float16 half8;
typedef __attribute__((ext_vector_type(4))) float f32x4;
union BF8 { uint32 u[4]; short8 v; };
union HF8 { uint32 u[4]; half8 v; };

__device__ __forceinline__ uint32 f2bf_pack(float x, float y) {
    uint32 ux = __float_as_uint(x);
    uint32 uy = __float_as_uint(y);
    uint32 bx = (ux + 0x7fffu + ((ux >> 16) & 1u)) >> 16;
    uint32 by = (uy + 0x7fffu + ((uy >> 16) & 1u)) >> 16;
    return (by << 16) | (bx & 0xffffu);
}

__device__ __forceinline__ uint32 f2h_pack(float x, float y) {
    __half2 h = __floats2half2_rn(x, y);
    return *(reinterpret_cast<uint32*>(&h));
}

// ---------------------------------------------------------------------------
// Kernel 0: item_emb fp32 -> bf16 packed words (IEB, 32 words/row)
// ---------------------------------------------------------------------------
__global__ __launch_bounds__(256) void k0_cvt(
    const float* __restrict__ src, uint32* __restrict__ dst)
{
    const int i = blockIdx.x * 256 + threadIdx.x;   // < IV*32 = 3.2M exact
    const float2 v = ((const float2*)src)[i];
    dst[i] = f2bf_pack(v.x, v.y);
}

// ---------------------------------------------------------------------------
// Kernel 0b: Wp (64 x NP fp32) -> WpB bf16 packed, layout [n][kw] kw=k-pair
// ---------------------------------------------------------------------------
__global__ __launch_bounds__(256) void k0b_cvt_wp(
    const float* __restrict__ Wp, uint32* __restrict__ WpB)
{
    const int n = blockIdx.x * 256 + threadIdx.x;
    const int kw = blockIdx.y;
    if (n < NP) {
        const float a = Wp[(size_t)(2*kw)*NP + n];
        const float b = Wp[(size_t)(2*kw+1)*NP + n];
        WpB[(size_t)n*32 + kw] = f2bf_pack(a, b);
    }
}

// ---------------------------------------------------------------------------
// Kernel 0c: Wf1/Wf2/Wf3 fp32 -> fp16 packed B-fragment layouts w/ K-padding.
// ---------------------------------------------------------------------------
__global__ __launch_bounds__(256) void k0c_cvt_wf(
    const float* __restrict__ Wf1, const float* __restrict__ Wf2,
    const float* __restrict__ Wf3, uint32* __restrict__ W1B,
    uint32* __restrict__ W2B, uint32* __restrict__ W3B)
{
    const int i = blockIdx.x * 256 + threadIdx.x;
    if (i < 13312) {
        const int n = i >> 6, kw = i & 63;
        W1B[i] = (n < 200) ? f2h_pack(Wf1[(size_t)(2*kw)*200 + n],
                                      Wf1[(size_t)(2*kw+1)*200 + n]) : 0u;
    } else if (i < 22272) {
        const int j = i - 13312, n = j / 112, kw = j % 112;
        W2B[j] = (kw < 100) ? f2h_pack(Wf2[(size_t)(2*kw)*80 + n],
                                       Wf2[(size_t)(2*kw+1)*80 + n]) : 0u;
    } else if (i < 25344) {
        const int j = i - 22272, n = j / 48, kw = j % 48;
        W3B[j] = (kw < 40) ? f2h_pack(Wf3[(size_t)(2*kw)*64 + n],
                                      Wf3[(size_t)(2*kw+1)*64 + n]) : 0u;
    }
}

// ---------------------------------------------------------------------------
// Kernel 1: gathers + attention + pooling.  grid=B, block=256.
// Register staging: wave w holds its 50 hist rows in 25 uint32/lane
// (lane kk holds word kk of 2 rows per iter).  One global touch per row,
// ~6 KB LDS -> 6 blocks/CU.  Scores via half-wave shuffle reduce.
// ---------------------------------------------------------------------------
__global__ __launch_bounds__(256, 6) void k1_gather_attn(
    const uint32* __restrict__ IEB,
    const float* __restrict__ item_emb, const float* __restrict__ user_emb,
    const float* __restrict__ W_if, const float* __restrict__ b_if,
    const float* __restrict__ W_uf, const float* __restrict__ b_uf,
    const float* __restrict__ item_features, const float* __restrict__ user_features,
    const int* __restrict__ user_id, const int* __restrict__ target_item_id,
    const int* __restrict__ hist_id, const int* __restrict__ hist_len,
    const int* __restrict__ pos_fb, const int* __restrict__ pos_mask,
    float* __restrict__ FUE, float* __restrict__ FIE, uint32* __restrict__ PINB)
{
    const int b = blockIdx.x;
    const int t = threadIdx.x;
    const int w = t >> 6;
    const int lane = t & 63;

    __shared__ __align__(16) float tgt[64];
    __shared__ float feats[256];
    __shared__ float ufe[64];
    __shared__ float scoreS[256];
    __shared__ float wred[8];
    __shared__ float part[256];
    __shared__ float part2[256];
    __shared__ int   hids[200];
    __shared__ int   cpi[104];
    __shared__ int   ptot[2];

    const int hl = hist_len[b];
    if (t < 200) hids[t] = hist_id[(size_t)b*LH + t];
    feats[t] = (t < 128) ? item_features[(size_t)b*128 + t]
                         : user_features[(size_t)b*128 + (t-128)];
    if (t < 64) tgt[t] = item_emb[(size_t)target_item_id[b]*64 + t];

    bool myAct = false; int myPid = 0;
    if (t < LFB) {
        myAct = pos_mask[(size_t)b*LFB + t] != 0;
        myPid = pos_fb[(size_t)b*LFB + t];
    }
    __syncthreads();   // sync0: tgt/hids/feats

    const int kk = lane & 31;          // word index within row
    const int hf = lane >> 5;          // which of 2 rows per iter
    const float2 tf = ((const float2*)tgt)[kk];

    // ---- register staging: one global touch per valid row ----
    uint32 rw[25];
    #pragma unroll
    for (int i = 0; i < 25; i++) {
        const int l = w*50 + i*2 + hf;
        rw[i] = (l < hl) ? IEB[(size_t)hids[l]*32 + kk] : 0u;
    }

    // ---- scores from registers (half-wave reduce; chains independent) ----
    #pragma unroll
    for (int i = 0; i < 25; i++) {
        const int l = w*50 + i*2 + hf;
        float sp = fmaf(__uint_as_float(rw[i] << 16), tf.x,
                        __uint_as_float(rw[i] & 0xffff0000u) * tf.y);
        sp += __shfl_xor(sp, 1, 64);
        sp += __shfl_xor(sp, 2, 64);
        sp += __shfl_xor(sp, 4, 64);
        sp += __shfl_xor(sp, 8, 64);
        sp += __shfl_xor(sp, 16, 64);
        if (kk == 0) scoreS[l] = sp * 0.125f;
    }

    // ---- pos-feedback compaction ballot (waves 0,1) ----
    int pre = 0;
    if (w < 2) {
        const unsigned long long bal = __ballot(myAct);
        pre = __popcll(bal & ((1ull << lane) - 1ull));
        if (lane == 0) ptot[w] = __popcll(bal);
    }
    __syncthreads();   // sync1: scoreS, ptot

    const int nP = ptot[0] + ptot[1];
    if (w < 2 && myAct) cpi[((w == 1) ? ptot[0] : 0) + pre] = myPid;

    float sc = (t < hl) ? scoreS[t] : -1e9f;
    float m = sc;
    #pragma unroll
    for (int off = 32; off >= 1; off >>= 1) m = fmaxf(m, __shfl_xor(m, off, 64));
    if (lane == 0) wred[w] = m;
    __syncthreads();   // sync2: wred max, cpi visible

    const float mx = fmaxf(fmaxf(wred[0], wred[1]), fmaxf(wred[2], wred[3]));
    const float ev = __expf(sc - mx);
    float s = ev;
    #pragma unroll
    for (int off = 32; off >= 1; off >>= 1) s += __shfl_xor(s, off, 64);
    if (lane == 0) wred[4 + w] = s;

    // ---- pos-mean gather over compacted list (all 4 waves) ----
    const int wk = lane >> 1;
    const int comp = lane & 1;
    {
        float pacc = 0.f;
        for (int i = w; i < nP; i += 4) {
            const uint32 wd = IEB[(size_t)cpi[i]*32 + wk];
            pacc += __uint_as_float(comp ? (wd & 0xffff0000u) : (wd << 16));
        }
        part2[w*64 + lane] = pacc;
    }

    // ---- feature embeddings (wave 0: item, wave 1: user) ----
    if (w == 0) {
        float acc = b_if[lane];
        #pragma unroll 4
        for (int k = 0; k < 128; k++) acc = fmaf(feats[k], W_if[k*64 + lane], acc);
        FIE[(size_t)b*64 + lane] = tgt[lane] + 1.f / (1.f + __expf(-acc));
    } else if (w == 1) {
        float acc = b_uf[lane];
        #pragma unroll 4
        for (int k = 0; k < 128; k++) acc = fmaf(feats[128 + k], W_uf[k*64 + lane], acc);
        ufe[lane] = 1.f / (1.f + __expf(-acc));
    }
    __syncthreads();   // sync3: wred sums

    const float S = wred[4] + wred[5] + wred[6] + wred[7];
    if (t < 200) scoreS[t] = ev / S;   // attn (0 for l >= hl)
    __syncthreads();   // sync4: attn visible

    // ---- pooled from registers ----
    {
        float ax = 0.f, ay = 0.f;
        #pragma unroll
        for (int i = 0; i < 25; i++) {
            const int l = w*50 + i*2 + hf;
            const float a = scoreS[l];
            ax = fmaf(a, __uint_as_float(rw[i] << 16),         ax);
            ay = fmaf(a, __uint_as_float(rw[i] & 0xffff0000u), ay);
        }
        ax += __shfl_xor(ax, 32, 64);
        ay += __shfl_xor(ay, 32, 64);
        if (hf == 0) {
            part[w*64 + 2*kk]     = ax;
            part[w*64 + 2*kk + 1] = ay;
        }
    }
    __syncthreads();   // sync5

    if (t < 64) {
        const float pooled = part[t] + part[64+t] + part[128+t] + part[192+t];
        const float pinv = (part2[t] + part2[64+t] + part2[128+t] + part2[192+t]) / (float)nP;
        FUE[(size_t)b*64 + t] = user_emb[(size_t)user_id[b]*64 + t] + ufe[t] + pooled;
        const float po = __shfl_xor(pinv, 1, 64);
        if ((t & 1) == 0) PINB[(size_t)b*32 + (t >> 1)] = f2bf_pack(pinv, po);
    }
}

// ---------------------------------------------------------------------------
// Kernel 2: total_prompt = relu(PIN @ Wp + bp) via MFMA bf16.
// ---------------------------------------------------------------------------
__global__ __launch_bounds__(256) void k2_prompt_gemm(
    const uint32* __restrict__ PINB, const uint32* __restrict__ WpB,
    const float* __restrict__ bp, float* __restrict__ TP32,
    uint32* __restrict__ TPN)
{
    __shared__ uint32 As[64*36];
    __shared__ uint32 Bs[128*36];
    __shared__ float bps[128];
    const int t = threadIdx.x;
    const int m0 = blockIdx.y * 64;
    const int n0 = blockIdx.x * 128;

    {
        const int m = t >> 2, kw0 = (t & 3) * 8;
        const uint4 u0 = *(const uint4*)&PINB[(size_t)(m0+m)*32 + kw0];
        const uint4 u1 = *(const uint4*)&PINB[(size_t)(m0+m)*32 + kw0 + 4];
        *(uint4*)&As[m*36 + kw0]     = u0;
        *(uint4*)&As[m*36 + kw0 + 4] = u1;
    }
    {
        const int n = t >> 1, kw0 = (t & 1) * 16;
        const int gn = n0 + n;
        if (gn < NP) {
            #pragma unroll
            for (int j = 0; j < 4; j++) {
                const uint4 u = *(const uint4*)&WpB[(size_t)gn*32 + kw0 + 4*j];
                *(uint4*)&Bs[n*36 + kw0 + 4*j] = u;
            }
        } else {
            #pragma unroll
            for (int j = 0; j < 16; j++) Bs[n*36 + kw0 + j] = 0u;
        }
    }
    if (t < 128) bps[t] = (n0 + t < NP) ? bp[n0 + t] : 0.f;
    __syncthreads();

    const int w = t >> 6, lane = t & 63, ml = lane & 15, q = lane >> 4;

    BF8 a0, a1;
    { uint4 u = *(const uint4*)&As[(w*16+ml)*36 + q*4];      a0.u[0]=u.x; a0.u[1]=u.y; a0.u[2]=u.z; a0.u[3]=u.w; }
    { uint4 u = *(const uint4*)&As[(w*16+ml)*36 + 16 + q*4]; a1.u[0]=u.x; a1.u[1]=u.y; a1.u[2]=u.z; a1.u[3]=u.w; }

    f32x4 c[8];
    #pragma unroll
    for (int nb = 0; nb < 8; nb++) {
        BF8 b0, b1;
        { uint4 u = *(const uint4*)&Bs[(nb*16+ml)*36 + q*4];      b0.u[0]=u.x; b0.u[1]=u.y; b0.u[2]=u.z; b0.u[3]=u.w; }
        { uint4 u = *(const uint4*)&Bs[(nb*16+ml)*36 + 16 + q*4]; b1.u[0]=u.x; b1.u[1]=u.y; b1.u[2]=u.z; b1.u[3]=u.w; }
        f32x4 cc = {0.f, 0.f, 0.f, 0.f};
        cc = __builtin_amdgcn_mfma_f32_16x16x32_bf16(a0.v, b0.v, cc, 0, 0, 0);
        cc = __builtin_amdgcn_mfma_f32_16x16x32_bf16(a1.v, b1.v, cc, 0, 0, 0);
        c[nb] = cc;
    }

    #pragma unroll
    for (int nb = 0; nb < 8; nb++) {
        const int n = n0 + nb*16 + ml;
        const float bv = bps[nb*16 + ml];
        #pragma unroll
        for (int r = 0; r < 4; r++) {
            const int m = m0 + w*16 + q*4 + r;
            const float v = fmaxf(c[nb][r] + bv, 0.f);
            const float vp = __shfl_xor(v, 1, 64);
            if (n < 32) {
                TP32[(size_t)m*32 + n] = v;
            } else if (n < NP && (ml & 1) == 0) {
                TPN[(size_t)m*1568 + ((n - 32) >> 1)] = f2bf_pack(v, vp);
            }
        }
    }
}

// ---------------------------------------------------------------------------
// Kernel 3: prompt hypernetwork via MFMA 16x16x32 bf16.  grid=B, block=256.
// Repack: coalesced TPN reads (kw-major thread map), transposed LDS [kw][n]
// (conflict-free writes); fragment loads 4x b32 (2-way = free).
// ---------------------------------------------------------------------------
__global__ __launch_bounds__(256) void k3_prompt_mlp(
    const uint32* __restrict__ IEB,
    const int* __restrict__ pos_fb, const int* __restrict__ pos_mask,
    const int* __restrict__ neg_fb, const int* __restrict__ neg_mask,
    const uint32* __restrict__ TPN,
    float* __restrict__ POS_PE, float* __restrict__ out)
{
    const int b = blockIdx.x, t = threadIdx.x;
    const int w = t >> 6, lane = t & 63;
    const int ml = lane & 15, q = lane >> 4;

    __shared__ uint32 w1T[32*36];   // [kw][n]
    __shared__ uint32 w2T[16*36];   // [kw][n]
    __shared__ float b1s[32], b2s[32];
    __shared__ float mPs[208], mNs[208];
    __shared__ int cids[208];
    __shared__ int tot[4];
    __shared__ float Hs[4][16*36];
    __shared__ float wps[4][4][16];

    bool act = false; int id = 0;
    if (t < LFB) {
        act = pos_mask[(size_t)b*LFB + t] != 0;
        id  = pos_fb[(size_t)b*LFB + t];
    } else if (t >= 128 && t < 128 + LFB) {
        act = neg_mask[(size_t)b*LFB + (t-128)] != 0;
        id  = neg_fb[(size_t)b*LFB + (t-128)];
    }
    const unsigned long long bal = __ballot(act);
    const int pre = __popcll(bal & ((1ull << lane) - 1ull));
    if (lane == 0) tot[w] = __popcll(bal);
    if (t < 208) cids[t] = 0;

    const uint32* pnw = TPN + (size_t)b*1568;
    #pragma unroll
    for (int it = 0; it < 4; it++) {
        const int i = t + 256*it;            // 0..1023
        const int kw = i >> 5, n = i & 31;   // coalesced reads
        const uint32 wa = pnw[kw*32 + (n >> 1)];
        const uint32 wb = pnw[kw*32 + 16 + (n >> 1)];
        const uint32 h0 = (n & 1) ? (wa >> 16) : (wa & 0xffffu);
        const uint32 h1 = (n & 1) ? (wb >> 16) : (wb & 0xffffu);
        w1T[kw*36 + n] = h0 | (h1 << 16);
    }
    #pragma unroll
    for (int it = 0; it < 2; it++) {
        const int i = t + 256*it;            // 0..511
        const int kw = i >> 5, n = i & 31;
        const uint32 wa = pnw[1040 + kw*32 + (n >> 1)];
        const uint32 wb = pnw[1040 + kw*32 + 16 + (n >> 1)];
        const uint32 h0 = (n & 1) ? (wa >> 16) : (wa & 0xffffu);
        const uint32 h1 = (n & 1) ? (wb >> 16) : (wb & 0xffffu);
        w2T[kw*36 + n] = h0 | (h1 << 16);
    }
    if (t < 16) {
        const uint32 wa = pnw[1024 + t];
        b1s[2*t]   = __uint_as_float(wa << 16);
        b1s[2*t+1] = __uint_as_float(wa & 0xffff0000u);
        const uint32 wb = pnw[1552 + t];
        b2s[2*t]   = __uint_as_float(wb << 16);
        b2s[2*t+1] = __uint_as_float(wb & 0xffff0000u);
    }
    __syncthreads();   // sync1

    const int nP = tot[0] + tot[1];
    const int nN = tot[2] + tot[3];
    const int R  = nP + nN;
    const int T  = (R + 15) >> 4;
    {
        int base = 0;
        if (w == 1) base = tot[0];
        else if (w == 2) base = nP;
        else if (w == 3) base = nP + tot[2];
        if (act) cids[base + pre] = id;
    }
    if (t < 208) {
        mPs[t] = (t < nP) ? 1.f : 0.f;
        mNs[t] = (t >= nP && t < R) ? 1.f : 0.f;
    }

    BF8 bf100, bf110, bf101, bf111, bf20, bf21;
    #pragma unroll
    for (int j = 0; j < 4; j++) {
        bf100.u[j] = w1T[(q*4+j)*36 + ml];
        bf110.u[j] = w1T[(16+q*4+j)*36 + ml];
        bf101.u[j] = w1T[(q*4+j)*36 + 16 + ml];
        bf111.u[j] = w1T[(16+q*4+j)*36 + 16 + ml];
        bf20.u[j]  = w2T[(q*4+j)*36 + ml];
        bf21.u[j]  = w2T[(q*4+j)*36 + 16 + ml];
    }
    __syncthreads();   // sync2: cids, mPs/mNs visible

    float accP0=0.f, accP1=0.f, accN0=0.f, accN1=0.f;
    float* hsw = Hs[w];

    for (int tile = w; tile < T; tile += 4) {
        const int g = tile*16 + ml;
        const uint32* rowp = IEB + (size_t)cids[g]*32;
        BF8 a0, a1;
        { uint4 u = *(const uint4*)(rowp + q*4);      a0.u[0]=u.x; a0.u[1]=u.y; a0.u[2]=u.z; a0.u[3]=u.w; }
        { uint4 u = *(const uint4*)(rowp + 16 + q*4); a1.u[0]=u.x; a1.u[1]=u.y; a1.u[2]=u.z; a1.u[3]=u.w; }

        f32x4 c0 = {0.f,0.f,0.f,0.f}, c1 = {0.f,0.f,0.f,0.f};
        c0 = __builtin_amdgcn_mfma_f32_16x16x32_bf16(a0.v, bf100.v, c0, 0, 0, 0);
        c0 = __builtin_amdgcn_mfma_f32_16x16x32_bf16(a1.v, bf110.v, c0, 0, 0, 0);
        c1 = __builtin_amdgcn_mfma_f32_16x16x32_bf16(a0.v, bf101.v, c1, 0, 0, 0);
        c1 = __builtin_amdgcn_mfma_f32_16x16x32_bf16(a1.v, bf111.v, c1, 0, 0, 0);

        #pragma unroll
        for (int r = 0; r < 4; r++) {
            const int row = q*4 + r;
            hsw[row*36 + ml]      = fmaxf(c0[r] + b1s[ml],      0.f);
            hsw[row*36 + 16 + ml] = fmaxf(c1[r] + b1s[16 + ml], 0.f);
        }
        asm volatile("s_waitcnt lgkmcnt(0)" ::: "memory");

        const float4 h0 = *(const float4*)&hsw[ml*36 + q*8];
        const float4 h1 = *(const float4*)&hsw[ml*36 + q*8 + 4];
        BF8 a2;
        a2.u[0] = f2bf_pack(h0.x, h0.y);
        a2.u[1] = f2bf_pack(h0.z, h0.w);
        a2.u[2] = f2bf_pack(h1.x, h1.y);
        a2.u[3] = f2bf_pack(h1.z, h1.w);

        f32x4 d0 = {0.f,0.f,0.f,0.f}, d1 = {0.f,0.f,0.f,0.f};
        d0 = __builtin_amdgcn_mfma_f32_16x16x32_bf16(a2.v, bf20.v, d0, 0, 0, 0);
        d1 = __builtin_amdgcn_mfma_f32_16x16x32_bf16(a2.v, bf21.v, d1, 0, 0, 0);

        #pragma unroll
        for (int r = 0; r < 4; r++) {
            const int g2 = tile*16 + q*4 + r;
            const float o0 = d0[r] + b2s[ml];
            const float o1 = d1[r] + b2s[16 + ml];
            accP0 = fmaf(mPs[g2], o0, accP0);
            accP1 = fmaf(mPs[g2], o1, accP1);
            accN0 = fmaf(mNs[g2], o0, accN0);
            accN1 = fmaf(mNs[g2], o1, accN1);
        }
    }

    accP0 += __shfl_xor(accP0, 16, 64); accP0 += __shfl_xor(accP0, 32, 64);
    accP1 += __shfl_xor(accP1, 16, 64); accP1 += __shfl_xor(accP1, 32, 64);
    accN0 += __shfl_xor(accN0, 16, 64); accN0 += __shfl_xor(accN0, 32, 64);
    accN1 += __shfl_xor(accN1, 16, 64); accN1 += __shfl_xor(accN1, 32, 64);
    if (lane < 16) {
        wps[w][0][lane] = accP0;
        wps[w][1][lane] = accP1;
        wps[w][2][lane] = accN0;
        wps[w][3][lane] = accN1;
    }
    __syncthreads();

    if (t < 32) {
        const int nt = t >> 4, p = t & 15;
        const float pp = wps[0][nt][p] + wps[1][nt][p] + wps[2][nt][p] + wps[3][nt][p];
        const float nn = wps[0][2+nt][p] + wps[1][2+nt][p] + wps[2][2+nt][p] + wps[3][2+nt][p];
        POS_PE[(size_t)b*32 + t] = pp;
        const float x = nn - pp;
        out[BN + (size_t)b*32 + t] = fmaxf(x, 0.f) + log1pf(__expf(-fabsf(x)));
    }
}

// ---------------------------------------------------------------------------
// Kernel 4: fused 3-layer fusion MLP + final dot via MFMA fp16.
// ---------------------------------------------------------------------------
__global__ __launch_bounds__(256) void k4_fusion(
    const float* __restrict__ FUE, const float* __restrict__ FIE,
    const float* __restrict__ POS_PE, const float* __restrict__ TP32,
    const uint32* __restrict__ W1B, const uint32* __restrict__ W2B,
    const uint32* __restrict__ W3B,
    const float* __restrict__ bf1, const float* __restrict__ bf2,
    float* __restrict__ out)
{
    const int b0 = blockIdx.x * 16;
    const int t = threadIdx.x;
    const int w = t >> 6, lane = t & 63, ml = lane & 15, q = lane >> 4;

    __shared__ uint32 w1s[208*68];
    __shared__ uint32 w2s[80*116];
    __shared__ uint32 w3s[64*52];
    __shared__ uint32 fin[16*68];
    __shared__ uint32 h1w[16*116];
    __shared__ uint32 h2w[16*52];
    __shared__ float fuels[16*68];
    __shared__ float b1s[208], b2s[80];
    __shared__ float part4[4][16];

    for (int i = t; i < 13312; i += 256) w1s[(i >> 6)*68 + (i & 63)] = W1B[i];
    for (int i = t; i < 8960; i += 256)  w2s[(i / 112)*116 + (i % 112)] = W2B[i];
    for (int i = t; i < 3072; i += 256)  w3s[(i / 48)*52 + (i % 48)] = W3B[i];

    #pragma unroll
    for (int it = 0; it < 4; it++) {
        const int i = t + 256*it;
        const int m2 = i >> 6, kw = i & 63;
        const int row = b0 + m2;
        float a, c;
        if (kw < 32)      { const float2 v = *(const float2*)&FIE[(size_t)row*64 + 2*kw];          a = v.x; c = v.y; }
        else if (kw < 48) { const float2 v = *(const float2*)&POS_PE[(size_t)row*32 + 2*kw - 64];  a = v.x; c = v.y; }
        else              { const float2 v = *(const float2*)&TP32[(size_t)row*32 + 2*kw - 96];    a = v.x; c = v.y; }
        fin[m2*68 + kw] = f2h_pack(a, c);
        fuels[m2*68 + kw] = FUE[(size_t)row*64 + kw];
    }
    if (t < 208) b1s[t] = (t < 200) ? bf1[t] : 0.f;
    if (t < 80)  b2s[t] = bf2[t];
    if (t < 128) {
        h1w[(t >> 3)*116 + 104 + (t & 7)] = 0u;
        h2w[(t >> 3)*52 + 40 + (t & 7)] = 0u;
    }
    __syncthreads();

    HF8 a1f[4];
    #pragma unroll
    for (int s = 0; s < 4; s++) {
        const uint4 u = *(const uint4*)&fin[ml*68 + s*16 + q*4];
        a1f[s].u[0] = u.x; a1f[s].u[1] = u.y; a1f[s].u[2] = u.z; a1f[s].u[3] = u.w;
    }
    for (int nt = w; nt < 13; nt += 4) {
        const uint32* wrow = &w1s[(16*nt + ml)*68];
        f32x4 c = {0.f, 0.f, 0.f, 0.f};
        #pragma unroll
        for (int s = 0; s < 4; s++) {
            HF8 bfm;
            const uint4 u = *(const uint4*)&wrow[s*16 + q*4];
            bfm.u[0] = u.x; bfm.u[1] = u.y; bfm.u[2] = u.z; bfm.u[3] = u.w;
            c = __builtin_amdgcn_mfma_f32_16x16x32_f16(a1f[s].v, bfm.v, c, 0, 0, 0);
        }
        const float bv = b1s[16*nt + ml];
        #pragma unroll
        for (int r = 0; r < 4; r++) {
            const float v = fmaxf(c[r] + bv, 0.f);
            const float vp = __shfl_xor(v, 1, 64);
            if ((ml & 1) == 0)
                h1w[(q*4 + r)*116 + 8*nt + (ml >> 1)] = f2h_pack(v, vp);
        }
    }
    __syncthreads();

    HF8 a2f[7];
    #pragma unroll
    for (int s = 0; s < 7; s++) {
        const uint4 u = *(const uint4*)&h1w[ml*116 + s*16 + q*4];
        a2f[s].u[0] = u.x; a2f[s].u[1] = u.y; a2f[s].u[2] = u.z; a2f[s].u[3] = u.w;
    }
    for (int nt = w; nt < 5; nt += 4) {
        const uint32* wrow = &w2s[(16*nt + ml)*116];
        f32x4 c = {0.f, 0.f, 0.f, 0.f};
        #pragma unroll
        for (int s = 0; s < 7; s++) {
            HF8 bfm;
            const uint4 u = *(const uint4*)&wrow[s*16 + q*4];
            bfm.u[0] = u.x; bfm.u[1] = u.y; bfm.u[2] = u.z; bfm.u[3] = u.w;
            c = __builtin_amdgcn_mfma_f32_16x16x32_f16(a2f[s].v, bfm.v, c, 0, 0, 0);
        }
        const float bv = b2s[16*nt + ml];
        #pragma unroll
        for (int r = 0; r < 4; r++) {
            const float v = fmaxf(c[r] + bv, 0.f);
            const float vp = __shfl_xor(v, 1, 64);
            if ((ml & 1) == 0)
                h2w[(q*4 + r)*52 + 8*nt + (ml >> 1)] = f2h_pack(v, vp);
        }
    }
    __syncthreads();

    {
        const int nt = w;
        const uint32* wrow = &w3s[(16*nt + ml)*52];
        f32x4 c = {0.f, 0.f, 0.f, 0.f};
        #pragma unroll
        for (int s = 0; s < 3; s++) {
            HF8 afm, bfm;
            const uint4 ua = *(const uint4*)&h2w[ml*52 + s*16 + q*4];
            afm.u[0] = ua.x; afm.u[1] = ua.y; afm.u[2] = ua.z; afm.u[3] = ua.w;
            const uint4 ub = *(const uint4*)&wrow[s*16 + q*4];
            bfm.u[0] = ub.x; bfm.u[1] = ub.y; bfm.u[2] = ub.z; bfm.u[3] = ub.w;
            c = __builtin_amdgcn_mfma_f32_16x16x32_f16(afm.v, bfm.v, c, 0, 0, 0);
        }
        #pragma unroll
        for (int r = 0; r < 4; r++) {
            float p = c[r] * fuels[(q*4 + r)*68 + 16*nt + ml];
            p += __shfl_xor(p, 1, 64);
            p += __shfl_xor(p, 2, 64);
            p += __shfl_xor(p, 4, 64);
            p += __shfl_xor(p, 8, 64);
            if (ml == 0) part4[w][q*4 + r] = p;
        }
    }
    __syncthreads();

    if (t < 16) out[b0 + t] = part4[0][t] + part4[1][t] + part4[2][t] + part4[3][t];
}

// ---------------------------------------------------------------------------
extern "C" void kernel_launch(void* const* d_in, const int* in_sizes, int n_in,
                              void* d_out, int out_size, void* d_ws, size_t ws_size,
                              hipStream_t stream)
{
    const float* item_emb       = (const float*)d_in[0];
    const float* user_emb       = (const float*)d_in[1];
    const float* W_if           = (const float*)d_in[2];
    const float* b_if           = (const float*)d_in[3];
    const float* W_uf           = (const float*)d_in[4];
    const float* b_uf           = (const float*)d_in[5];
    const float* Wp             = (const float*)d_in[6];
    const float* bp             = (const float*)d_in[7];
    const float* Wf1            = (const float*)d_in[8];
    const float* bf1            = (const float*)d_in[9];
    const float* Wf2            = (const float*)d_in[10];
    const float* bf2            = (const float*)d_in[11];
    const float* Wf3            = (const float*)d_in[12];
    const float* item_features  = (const float*)d_in[13];
    const float* user_features  = (const float*)d_in[14];
    const int*   user_id        = (const int*)d_in[15];
    const int*   target_item_id = (const int*)d_in[16];
    const int*   history_item_id= (const int*)d_in[17];
    const int*   history_len    = (const int*)d_in[18];
    const int*   pos_fb         = (const int*)d_in[19];
    const int*   pos_mask       = (const int*)d_in[20];
    const int*   neg_fb         = (const int*)d_in[21];
    const int*   neg_mask       = (const int*)d_in[22];

    float* out = (float*)d_out;
    float* ws  = (float*)d_ws;

    uint32* IEB  = (uint32*)ws;                       // IV*32
    uint32* WpB  = IEB + (size_t)IV*32;               // NP*32
    uint32* W1B  = WpB + (size_t)NP*32;               // 13312
    uint32* W2B  = W1B + 13312;                       // 8960
    uint32* W3B  = W2B + 8960;                        // 3072
    uint32* PINB = W3B + 3072;                        // BN*32
    float*  FUE  = (float*)(PINB + (size_t)BN*32);
    float*  FIE  = FUE + (size_t)BN*64;
    float*  TP32 = FIE + (size_t)BN*64;               // BN*32
    uint32* TPN  = (uint32*)(TP32 + (size_t)BN*32);   // BN*1568
    float*  PPE  = (float*)(TPN + (size_t)BN*1568);

    k0_cvt<<<dim3(IV*32/256), dim3(256), 0, stream>>>(item_emb, IEB);
    k0b_cvt_wp<<<dim3(13, 32), dim3(256), 0, stream>>>(Wp, WpB);
    k0c_cvt_wf<<<dim3(99), dim3(256), 0, stream>>>(Wf1, Wf2, Wf3, W1B, W2B, W3B);

    k1_gather_attn<<<dim3(BN), dim3(256), 0, stream>>>(
        IEB, item_emb, user_emb, W_if, b_if, W_uf, b_uf,
        item_features, user_features, user_id, target_item_id,
        history_item_id, history_len, pos_fb, pos_mask,
        FUE, FIE, PINB);

    k2_prompt_gemm<<<dim3(25, 64), dim3(256), 0, stream>>>(PINB, WpB, bp, TP32, TPN);

    k3_prompt_mlp<<<dim3(BN), dim3(256), 0, stream>>>(
        IEB, pos_fb, pos_mask, neg_fb, neg_mask, TPN, PPE, out);

    k4_fusion<<<dim3(BN/16), dim3(256), 0, stream>>>(
        FUE, FIE, PPE, TP32, W1B, W2B, W3B, bf1, bf2, out);
}